// Round 9
// baseline (131.032 us; speedup 1.0000x reference)
//
#include <hip/hip_runtime.h>
#include <math.h>

typedef unsigned short u16;
typedef unsigned int   u32;
typedef __attribute__((ext_vector_type(8))) short bf16x8;
typedef __attribute__((ext_vector_type(4))) float f32x4;
typedef __attribute__((ext_vector_type(4))) u32   u32x4;

#define NB 8
#define NC 512
#define NS 1024
#define NH 8
#define ND 64
#define NG 32
#define CPG 16
#define SCALE_Q 0.18033688f  /* 0.125 * log2(e): softmax runs in exp2 domain */

__device__ __forceinline__ u16 f2bf(float x) {
  u32 u = __builtin_bit_cast(u32, x);
  u = u + 0x7fffu + ((u >> 16) & 1u);
  return (u16)(u >> 16);
}

__device__ __forceinline__ float exp2_fast(float x) {
  float r;
  asm("v_exp_f32 %0, %1" : "=v"(r) : "v"(x));
  return r;
}

__device__ __forceinline__ u32 cvtpk_bf16(float lo, float hi) {
  u32 r;
  asm("v_cvt_pk_bf16_f32 %0, %1, %2" : "=v"(r) : "v"(lo), "v"(hi));
  return r;
}

__device__ __forceinline__ void gll16(void* l, const void* g) {
  __builtin_amdgcn_global_load_lds((const __attribute__((address_space(1))) void*)g,
                                   (__attribute__((address_space(3))) void*)l, 16, 0, 0);
}

__device__ __forceinline__ void drain_vm() {
  asm volatile("s_waitcnt vmcnt(0)" ::: "memory");
}

// ---------------- K0: weight fp32 -> bf16 ----------------
__global__ __launch_bounds__(256) void wconv_kernel(const float* __restrict__ qkvw,
                                                    const float* __restrict__ outw,
                                                    u16* __restrict__ wq,
                                                    u16* __restrict__ wo) {
  int i = (blockIdx.x * 256 + threadIdx.x) * 4;
  const int NQ = 3 * NC * NC;
  const float* src;
  u16* dst;
  int off;
  if (i < NQ) { src = qkvw; dst = wq; off = i; }
  else        { src = outw; dst = wo; off = i - NQ; }
  float4 v = *(const float4*)(src + off);
  u32 lo = (u32)f2bf(v.x) | ((u32)f2bf(v.y) << 16);
  u32 hi = (u32)f2bf(v.z) | ((u32)f2bf(v.w) << 16);
  u32* p = (u32*)(dst + off);
  p[0] = lo; p[1] = hi;
}

// ---------------- K1: GroupNorm -> xnT[b][p][c] bf16 ----------------
__global__ __launch_bounds__(256) void gn_kernel(const float* __restrict__ x,
                                                 const float* __restrict__ gamma,
                                                 const float* __restrict__ beta,
                                                 u16* __restrict__ xnT) {
  __shared__ float red[10];
  const int t = threadIdx.x;
  const int wave = t >> 6, lane = t & 63;
  const int b = blockIdx.x >> 5, g = blockIdx.x & 31;
  const float* xb = x + (size_t)(b * NC + g * CPG) * NS;

  float s = 0.f, ss = 0.f;
#pragma unroll
  for (int i = 0; i < 16; ++i) {
    int idx = t + i * 256;
    float4 v = ((const float4*)xb)[idx];
    s  += (v.x + v.y) + (v.z + v.w);
    ss += (v.x * v.x + v.y * v.y) + (v.z * v.z + v.w * v.w);
  }
#pragma unroll
  for (int m2 = 32; m2; m2 >>= 1) { s += __shfl_xor(s, m2); ss += __shfl_xor(ss, m2); }
  if (lane == 0) { red[wave] = s; red[4 + wave] = ss; }
  __syncthreads();
  if (t == 0) {
    float fs  = (red[0] + red[1]) + (red[2] + red[3]);
    float fss = (red[4] + red[5]) + (red[6] + red[7]);
    float mean = fs * (1.f / 16384.f);
    float var  = fss * (1.f / 16384.f) - mean * mean;
    red[8] = mean;
    red[9] = rsqrtf(fmaxf(var, 0.f) + 1e-5f);
  }
  __syncthreads();
  const float mean = red[8], inv = red[9];
  float gm[CPG], bt[CPG];
#pragma unroll
  for (int ci = 0; ci < CPG; ++ci) {
    float ga = gamma[g * CPG + ci];
    gm[ci] = ga * inv;
    bt[ci] = beta[g * CPG + ci] - mean * inv * ga;
  }
#pragma unroll
  for (int i = 0; i < 4; ++i) {
    int p = t + i * 256;
    u32 pk[8];
#pragma unroll
    for (int ci = 0; ci < CPG; ci += 2) {
      float v0 = xb[(size_t)ci * NS + p]       * gm[ci]     + bt[ci];
      float v1 = xb[(size_t)(ci + 1) * NS + p] * gm[ci + 1] + bt[ci + 1];
      pk[ci >> 1] = (u32)f2bf(v0) | ((u32)f2bf(v1) << 16);
    }
    u32* dst = (u32*)(xnT + (size_t)(b * NS + p) * NC + g * CPG);
#pragma unroll
    for (int q2 = 0; q2 < 8; ++q2) dst[q2] = pk[q2];
  }
}

// ---------------- K2: QKV gemm_bt (2-phase double-buffered) ----------------
__global__ __launch_bounds__(256) void qkv_gemm(const u16* __restrict__ A,
                                                const u16* __restrict__ BT,
                                                const float* __restrict__ bias,
                                                u16* __restrict__ qb,
                                                u16* __restrict__ kb,
                                                u16* __restrict__ vb) {
  __shared__ char lds[32768];  // 2 x (A 8KB + B 8KB)
  const int t = threadIdx.x, wave = t >> 6, lane = t & 63;
  const int bn = blockIdx.x * 128;
  const int bm = blockIdx.y * 128;
  const int bb = blockIdx.z;
  const u16* Bt = BT + (size_t)bb * NS * NC;
  const int wm = wave >> 1, wn = wave & 1;
  f32x4 acc[4][4];
#pragma unroll
  for (int i = 0; i < 4; ++i)
#pragma unroll
    for (int j = 0; j < 4; ++j) acc[i][j] = (f32x4){0.f, 0.f, 0.f, 0.f};

  int c0 = t, c1 = 256 + t;
  int r0 = c0 >> 2, r1 = c1 >> 2;
  int h0 = (c0 & 3) ^ ((c0 >> 3) & 3), h1 = (c1 & 3) ^ ((c1 >> 3) & 3);
  const u16* a0 = A  + (size_t)(bm + r0) * NC + h0 * 8;
  const u16* a1 = A  + (size_t)(bm + r1) * NC + h1 * 8;
  const u16* b0 = Bt + (size_t)(bn + r0) * NC + h0 * 8;
  const u16* b1 = Bt + (size_t)(bn + r1) * NC + h1 * 8;

  gll16(lds + c0 * 16, a0); gll16(lds + c1 * 16, a1);
  gll16(lds + 8192 + c0 * 16, b0); gll16(lds + 8192 + c1 * 16, b1);
  __syncthreads();

  for (int ks = 0; ks < 16; ++ks) {
    const char* cur = lds + ((ks & 1) << 14);
    if (ks < 15) {
      char* nxt = lds + (((ks + 1) & 1) << 14);
      int ko = (ks + 1) * 32;
      gll16(nxt + c0 * 16,        a0 + ko);
      gll16(nxt + c1 * 16,        a1 + ko);
      gll16(nxt + 8192 + c0 * 16, b0 + ko);
      gll16(nxt + 8192 + c1 * 16, b1 + ko);
    }
    bf16x8 af[4], bfr[4];
#pragma unroll
    for (int mf = 0; mf < 4; ++mf) {
      int row = wm * 64 + mf * 16 + (lane & 15);
      int cb = ((lane >> 4) * 16) ^ (((row >> 1) & 3) << 4);
      af[mf] = *(const bf16x8*)(cur + row * 64 + cb);
    }
#pragma unroll
    for (int nf = 0; nf < 4; ++nf) {
      int row = wn * 64 + nf * 16 + (lane & 15);
      int cb = ((lane >> 4) * 16) ^ (((row >> 1) & 3) << 4);
      bfr[nf] = *(const bf16x8*)(cur + 8192 + row * 64 + cb);
    }
#pragma unroll
    for (int mf = 0; mf < 4; ++mf)
#pragma unroll
      for (int nf = 0; nf < 4; ++nf)
        acc[mf][nf] = __builtin_amdgcn_mfma_f32_16x16x32_bf16(af[mf], bfr[nf], acc[mf][nf], 0, 0, 0);
    __syncthreads();
  }
#pragma unroll
  for (int mf = 0; mf < 4; ++mf) {
#pragma unroll
    for (int j = 0; j < 4; ++j) {
      int o = bm + wm * 64 + mf * 16 + (lane >> 4) * 4 + j;
      int n = o / 192;
      int r = o - n * 192;
      float bv = bias[o];
      size_t hb = (size_t)(bb * NH + n);
#pragma unroll
      for (int nf = 0; nf < 4; ++nf) {
        int p = bn + wn * 64 + nf * 16 + (lane & 15);
        float val = acc[mf][nf][j] + bv;
        if (r < 64)       qb[(hb * NS + p) * ND + r] = f2bf(val * SCALE_Q);
        else if (r < 128) kb[(hb * NS + p) * ND + (r - 64)] = f2bf(val);
        else              vb[(hb * ND + (r - 128)) * NS + p] = f2bf(val);
      }
    }
  }
}

// ---------------- K3: flash attention, QBLK=32 per wave (R8-identical) -------
__global__ __launch_bounds__(256) void attn_kernel(const u16* __restrict__ qbuf,
                                                   const u16* __restrict__ kbuf,
                                                   const u16* __restrict__ vbuf,
                                                   u16* __restrict__ aoT) {
  __shared__ char lds[32768];  // 2 x (K 8KB + V 8KB)
  const int t = threadIdx.x, wave = t >> 6, lane = t & 63;
  const int qblk = blockIdx.x;   // 8 blocks of 128 q rows
  const int bn = blockIdx.y;
  const int b = bn >> 3, n = bn & 7;
  const u16* qp = qbuf + (size_t)bn * NS * ND;
  const char* kpb = (const char*)(kbuf + (size_t)bn * NS * ND);
  const char* vpb = (const char*)(vbuf + (size_t)bn * ND * NS);
  const int g = lane >> 4, q = lane & 15;
  const int qrowbase = qblk * 128 + wave * 32;

  bf16x8 bq[2][2];
#pragma unroll
  for (int qf = 0; qf < 2; ++qf) {
    const u16* qr = qp + (size_t)(qrowbase + qf * 16 + q) * ND + g * 8;
    bq[qf][0] = *(const bf16x8*)(qr);
    bq[qf][1] = *(const bf16x8*)(qr + 32);
  }
  int c0 = t, c1 = 256 + t;
  int lam0 = c0 >> 3, lam1 = c1 >> 3;
  int chs0 = (c0 & 7) ^ (lam0 & 7), chs1 = (c1 & 7) ^ (lam1 & 7);
  int kv0 = ((lam0 >> 5) & 1) * 32 + ((lam0 >> 4) & 1) * 4 + ((lam0 >> 2) & 3) * 8 + (lam0 & 3);
  int kv1 = ((lam1 >> 5) & 1) * 32 + ((lam1 >> 4) & 1) * 4 + ((lam1 >> 2) & 3) * 8 + (lam1 & 3);
  const char* ksrc0 = kpb + kv0 * 128 + chs0 * 16;
  const char* ksrc1 = kpb + kv1 * 128 + chs1 * 16;
  const char* vsrc0 = vpb + lam0 * 2048 + chs0 * 16;
  const char* vsrc1 = vpb + lam1 * 2048 + chs1 * 16;
  const int koffA = q * 128 + (((0 * 4 + g) ^ (q & 7)) << 4);
  const int koffB = q * 128 + (((1 * 4 + g) ^ (q & 7)) << 4);

  float m[2], l[2];
  f32x4 oacc[4][2];  // [df][qf]
#pragma unroll
  for (int qf = 0; qf < 2; ++qf) { m[qf] = -1e30f; l[qf] = 0.f; }
#pragma unroll
  for (int df = 0; df < 4; ++df)
#pragma unroll
    for (int qf = 0; qf < 2; ++qf) oacc[df][qf] = (f32x4){0.f, 0.f, 0.f, 0.f};

  gll16(lds + c0 * 16,        ksrc0);
  gll16(lds + c1 * 16,        ksrc1);
  gll16(lds + 8192 + c0 * 16, vsrc0);
  gll16(lds + 8192 + c1 * 16, vsrc1);
  drain_vm();
  __syncthreads();

  for (int kb = 0; kb < 16; ++kb) {
    const char* cur = lds + ((kb & 1) << 14);
    if (kb < 15) {
      char* nxt = lds + (((kb + 1) & 1) << 14);
      size_t ko = (size_t)(kb + 1) * 8192;
      size_t vo = (size_t)(kb + 1) * 128;
      gll16(nxt + c0 * 16,        ksrc0 + ko);
      gll16(nxt + c1 * 16,        ksrc1 + ko);
      gll16(nxt + 8192 + c0 * 16, vsrc0 + vo);
      gll16(nxt + 8192 + c1 * 16, vsrc1 + vo);
    }
    bf16x8 kf0[4], kf1[4];
#pragma unroll
    for (int cf = 0; cf < 4; ++cf) {
      kf0[cf] = *(const bf16x8*)(cur + cf * 2048 + koffA);
      kf1[cf] = *(const bf16x8*)(cur + cf * 2048 + koffB);
    }
    f32x4 s[2][4];  // [qf][cf]
#pragma unroll
    for (int qf = 0; qf < 2; ++qf)
#pragma unroll
      for (int cf = 0; cf < 4; ++cf) {
        f32x4 s0 = __builtin_amdgcn_mfma_f32_16x16x32_bf16(kf0[cf], bq[qf][0], (f32x4){0.f, 0.f, 0.f, 0.f}, 0, 0, 0);
        s[qf][cf] = __builtin_amdgcn_mfma_f32_16x16x32_bf16(kf1[cf], bq[qf][1], s0, 0, 0, 0);
      }
    const char* curv = cur + 8192;
    bf16x8 vf0[4], vf1[4];
#pragma unroll
    for (int df = 0; df < 4; ++df) {
      vf0[df] = *(const bf16x8*)(curv + df * 2048 + koffA);
      vf1[df] = *(const bf16x8*)(curv + df * 2048 + koffB);
    }
#pragma unroll
    for (int qf = 0; qf < 2; ++qf) {
      f32x4 s0 = s[qf][0], s1 = s[qf][1], s2 = s[qf][2], s3 = s[qf][3];
      float mx = fmaxf(fmaxf(fmaxf(s0[0], s0[1]), fmaxf(s0[2], s0[3])),
                       fmaxf(fmaxf(s1[0], s1[1]), fmaxf(s1[2], s1[3])));
      mx = fmaxf(mx, fmaxf(fmaxf(fmaxf(s2[0], s2[1]), fmaxf(s2[2], s2[3])),
                           fmaxf(fmaxf(s3[0], s3[1]), fmaxf(s3[2], s3[3]))));
      if (!__all(mx - m[qf] <= 8.f)) {
        float mxr = fmaxf(mx, __shfl_xor(mx, 16));
        mxr = fmaxf(mxr, __shfl_xor(mxr, 32));
        float mn = fmaxf(m[qf], mxr);
        float sc = exp2_fast(m[qf] - mn);
        m[qf] = mn;
        l[qf] *= sc;
#pragma unroll
        for (int df = 0; df < 4; ++df) {
          f32x4 o2 = oacc[df][qf];
          o2[0] *= sc; o2[1] *= sc; o2[2] *= sc; o2[3] *= sc;
          oacc[df][qf] = o2;
        }
      }
      float mm = m[qf], ll = l[qf];
      float p00 = exp2_fast(s0[0] - mm), p01 = exp2_fast(s0[1] - mm);
      float p02 = exp2_fast(s0[2] - mm), p03 = exp2_fast(s0[3] - mm);
      float p10 = exp2_fast(s1[0] - mm), p11 = exp2_fast(s1[1] - mm);
      float p12 = exp2_fast(s1[2] - mm), p13 = exp2_fast(s1[3] - mm);
      float p20 = exp2_fast(s2[0] - mm), p21 = exp2_fast(s2[1] - mm);
      float p22 = exp2_fast(s2[2] - mm), p23 = exp2_fast(s2[3] - mm);
      float p30 = exp2_fast(s3[0] - mm), p31 = exp2_fast(s3[1] - mm);
      float p32 = exp2_fast(s3[2] - mm), p33 = exp2_fast(s3[3] - mm);
      ll += ((p00 + p01) + (p02 + p03)) + ((p10 + p11) + (p12 + p13)) +
            ((p20 + p21) + (p22 + p23)) + ((p30 + p31) + (p32 + p33));
      l[qf] = ll;
      u32x4 w0, w1;
      w0[0] = cvtpk_bf16(p00, p01); w0[1] = cvtpk_bf16(p02, p03);
      w0[2] = cvtpk_bf16(p10, p11); w0[3] = cvtpk_bf16(p12, p13);
      w1[0] = cvtpk_bf16(p20, p21); w1[1] = cvtpk_bf16(p22, p23);
      w1[2] = cvtpk_bf16(p30, p31); w1[3] = cvtpk_bf16(p32, p33);
      bf16x8 pb0 = __builtin_bit_cast(bf16x8, w0);
      bf16x8 pb1 = __builtin_bit_cast(bf16x8, w1);
#pragma unroll
      for (int df = 0; df < 4; ++df) {
        oacc[df][qf] = __builtin_amdgcn_mfma_f32_16x16x32_bf16(vf0[df], pb0, oacc[df][qf], 0, 0, 0);
        oacc[df][qf] = __builtin_amdgcn_mfma_f32_16x16x32_bf16(vf1[df], pb1, oacc[df][qf], 0, 0, 0);
      }
    }
    drain_vm();
    __syncthreads();
  }
  char* myT = lds + wave * 2048;
#pragma unroll
  for (int qf = 0; qf < 2; ++qf) {
    float ll = l[qf];
    ll += __shfl_xor(ll, 16);
    ll += __shfl_xor(ll, 32);
    const float inv = 1.f / ll;
#pragma unroll
    for (int df = 0; df < 4; ++df)
#pragma unroll
      for (int h = 0; h < 2; ++h) {
        u32 w = cvtpk_bf16(oacc[df][qf][2 * h] * inv, oacc[df][qf][2 * h + 1] * inv);
        int X = (df * 16 + 4 * g + 2 * h) * 2;
        *(u32*)(myT + q * 128 + (X ^ ((q & 7) << 4))) = w;
      }
#pragma unroll
    for (int h = 0; h < 2; ++h) {
      int q2 = h * 8 + (lane >> 3);
      int c = lane & 7;
      bf16x8 vrow = *(const bf16x8*)(myT + q2 * 128 + ((c * 16) ^ ((q2 & 7) << 4)));
      int prow = qrowbase + qf * 16 + q2;
      *(bf16x8*)(aoT + (size_t)(b * NS + prow) * NC + n * 64 + c * 8) = vrow;
    }
  }
}

// ---------------- K4: out gemm_bt + bias + residual (R5 128x128, 2-phase) ----
__global__ __launch_bounds__(256) void out_gemm(const u16* __restrict__ A,
                                                const u16* __restrict__ BT,
                                                const float* __restrict__ bias,
                                                const float* __restrict__ xres,
                                                float* __restrict__ out) {
  __shared__ char lds[32768];
  const int t = threadIdx.x, wave = t >> 6, lane = t & 63;
  const int bn = blockIdx.x * 128;
  const int bm = blockIdx.y * 128;
  const int bb = blockIdx.z;
  const u16* Bt = BT + (size_t)bb * NS * NC;
  const int wm = wave >> 1, wn = wave & 1;
  f32x4 acc[4][4];
#pragma unroll
  for (int i = 0; i < 4; ++i)
#pragma unroll
    for (int j = 0; j < 4; ++j) acc[i][j] = (f32x4){0.f, 0.f, 0.f, 0.f};

  int c0 = t, c1 = 256 + t;
  int r0 = c0 >> 2, r1 = c1 >> 2;
  int h0 = (c0 & 3) ^ ((c0 >> 3) & 3), h1 = (c1 & 3) ^ ((c1 >> 3) & 3);
  const u16* a0 = A  + (size_t)(bm + r0) * NC + h0 * 8;
  const u16* a1 = A  + (size_t)(bm + r1) * NC + h1 * 8;
  const u16* b0 = Bt + (size_t)(bn + r0) * NC + h0 * 8;
  const u16* b1 = Bt + (size_t)(bn + r1) * NC + h1 * 8;

  gll16(lds + c0 * 16, a0); gll16(lds + c1 * 16, a1);
  gll16(lds + 8192 + c0 * 16, b0); gll16(lds + 8192 + c1 * 16, b1);
  __syncthreads();

  for (int ks = 0; ks < 16; ++ks) {
    const char* cur = lds + ((ks & 1) << 14);
    if (ks < 15) {
      char* nxt = lds + (((ks + 1) & 1) << 14);
      int ko = (ks + 1) * 32;
      gll16(nxt + c0 * 16,        a0 + ko);
      gll16(nxt + c1 * 16,        a1 + ko);
      gll16(nxt + 8192 + c0 * 16, b0 + ko);
      gll16(nxt + 8192 + c1 * 16, b1 + ko);
    }
    bf16x8 af[4], bfr[4];
#pragma unroll
    for (int mf = 0; mf < 4; ++mf) {
      int row = wm * 64 + mf * 16 + (lane & 15);
      int cb = ((lane >> 4) * 16) ^ (((row >> 1) & 3) << 4);
      af[mf] = *(const bf16x8*)(cur + row * 64 + cb);
    }
#pragma unroll
    for (int nf = 0; nf < 4; ++nf) {
      int row = wn * 64 + nf * 16 + (lane & 15);
      int cb = ((lane >> 4) * 16) ^ (((row >> 1) & 3) << 4);
      bfr[nf] = *(const bf16x8*)(cur + 8192 + row * 64 + cb);
    }
#pragma unroll
    for (int mf = 0; mf < 4; ++mf)
#pragma unroll
      for (int nf = 0; nf < 4; ++nf)
        acc[mf][nf] = __builtin_amdgcn_mfma_f32_16x16x32_bf16(af[mf], bfr[nf], acc[mf][nf], 0, 0, 0);
    __syncthreads();
  }
#pragma unroll
  for (int mf = 0; mf < 4; ++mf) {
#pragma unroll
    for (int j = 0; j < 4; ++j) {
      int o = bm + wm * 64 + mf * 16 + (lane >> 4) * 4 + j;
      float bv = bias[o];
#pragma unroll
      for (int nf = 0; nf < 4; ++nf) {
        int p = bn + wn * 64 + nf * 16 + (lane & 15);
        size_t idx = (size_t)(bb * NC + o) * NS + p;
        out[idx] = acc[mf][nf][j] + bv + xres[idx];
      }
    }
  }
}

extern "C" void kernel_launch(void* const* d_in, const int* in_sizes, int n_in,
                              void* d_out, int out_size, void* d_ws, size_t ws_size,
                              hipStream_t stream) {
  const float* x     = (const float*)d_in[0];
  const float* gn_w  = (const float*)d_in[1];
  const float* gn_b  = (const float*)d_in[2];
  const float* qkv_w = (const float*)d_in[3];
  const float* qkv_b = (const float*)d_in[4];
  const float* out_w = (const float*)d_in[5];
  const float* out_b = (const float*)d_in[6];
  float* out = (float*)d_out;
  char* ws = (char*)d_ws;

  u16* wq  = (u16*)(ws);
  u16* wo  = (u16*)(ws + 1572864);
  u16* xnT = (u16*)(ws + 2097152);
  u16* kb  = (u16*)(ws + 10485760);
  u16* vb  = (u16*)(ws + 18874368);
  u16* aoT = (u16*)(ws + 2097152);   // overlaps xnT (sequentially dead)
  u16* qb  = (u16*)d_out;            // scratch use of d_out; overwritten by out_gemm

  wconv_kernel<<<dim3(1024), dim3(256), 0, stream>>>(qkv_w, out_w, wq, wo);
  gn_kernel<<<dim3(NB * NG), dim3(256), 0, stream>>>(x, gn_w, gn_b, xnT);
  qkv_gemm<<<dim3(8, 12, NB), dim3(256), 0, stream>>>(wq, xnT, qkv_b, qb, kb, vb);
  // MEASUREMENT ROUND: attn launched twice (idempotent, deterministic).
  // delta(total) vs R8 = one attn duration; if >=40us it enters rocprof top-5
  // with full counters. Remove the duplicate next round.
  attn_kernel<<<dim3(8, NB * NH), dim3(256), 0, stream>>>(qb, kb, vb, aoT);
  attn_kernel<<<dim3(8, NB * NH), dim3(256), 0, stream>>>(qb, kb, vb, aoT);
  out_gemm<<<dim3(8, 4, NB), dim3(256), 0, stream>>>(wo, aoT, out_b, x, out);
}

// Round 10
// 97.158 us; speedup vs baseline: 1.3486x; 1.3486x over previous
//
#include <hip/hip_runtime.h>
#include <math.h>

typedef unsigned short u16;
typedef unsigned int   u32;
typedef __attribute__((ext_vector_type(8))) short bf16x8;
typedef __attribute__((ext_vector_type(4))) float f32x4;
typedef __attribute__((ext_vector_type(4))) u32   u32x4;

#define NB 8
#define NC 512
#define NS 1024
#define NH 8
#define ND 64
#define NG 32
#define CPG 16
#define SCALE_Q 0.18033688f  /* 0.125 * log2(e): softmax runs in exp2 domain */

__device__ __forceinline__ u16 f2bf(float x) {
  u32 u = __builtin_bit_cast(u32, x);
  u = u + 0x7fffu + ((u >> 16) & 1u);
  return (u16)(u >> 16);
}

__device__ __forceinline__ float exp2_fast(float x) {
  float r;
  asm("v_exp_f32 %0, %1" : "=v"(r) : "v"(x));
  return r;
}

__device__ __forceinline__ u32 cvtpk_bf16(float lo, float hi) {
  u32 r;
  asm("v_cvt_pk_bf16_f32 %0, %1, %2" : "=v"(r) : "v"(lo), "v"(hi));
  return r;
}

__device__ __forceinline__ void gll16(void* l, const void* g) {
  __builtin_amdgcn_global_load_lds((const __attribute__((address_space(1))) void*)g,
                                   (__attribute__((address_space(3))) void*)l, 16, 0, 0);
}

__device__ __forceinline__ void drain_vm() {
  asm volatile("s_waitcnt vmcnt(0)" ::: "memory");
}

// ---------------- K0: weight fp32 -> bf16 ----------------
__global__ __launch_bounds__(256) void wconv_kernel(const float* __restrict__ qkvw,
                                                    const float* __restrict__ outw,
                                                    u16* __restrict__ wq,
                                                    u16* __restrict__ wo) {
  int i = (blockIdx.x * 256 + threadIdx.x) * 4;
  const int NQ = 3 * NC * NC;
  const float* src;
  u16* dst;
  int off;
  if (i < NQ) { src = qkvw; dst = wq; off = i; }
  else        { src = outw; dst = wo; off = i - NQ; }
  float4 v = *(const float4*)(src + off);
  u32 lo = (u32)f2bf(v.x) | ((u32)f2bf(v.y) << 16);
  u32 hi = (u32)f2bf(v.z) | ((u32)f2bf(v.w) << 16);
  u32* p = (u32*)(dst + off);
  p[0] = lo; p[1] = hi;
}

// ---------------- K1: GroupNorm -> xnT[b][p][c] bf16 (single-pass, 1024 thr) --
// Thread t holds 4 channels (cq = (t&3)*4 .. +4) x 4 pixels (p4 = t>>2) of x in
// registers; reduction then normalize+write from regs (no second global read).
__global__ __launch_bounds__(1024) void gn_kernel(const float* __restrict__ x,
                                                  const float* __restrict__ gamma,
                                                  const float* __restrict__ beta,
                                                  u16* __restrict__ xnT) {
  __shared__ float red[34];
  const int t = threadIdx.x;
  const int wave = t >> 6, lane = t & 63;
  const int b = blockIdx.x >> 5, g = blockIdx.x & 31;
  const float* xb = x + (size_t)(b * NC + g * CPG) * NS;
  const int p4 = t >> 2;        // pixel group [0,256)
  const int cq = (t & 3) * 4;   // channel base within the 16-ch group

  float4 hold[4];
  float s = 0.f, ss = 0.f;
#pragma unroll
  for (int i = 0; i < 4; ++i) {
    float4 v = ((const float4*)xb)[(cq + i) * 256 + p4];
    hold[i] = v;
    s  += (v.x + v.y) + (v.z + v.w);
    ss += (v.x * v.x + v.y * v.y) + (v.z * v.z + v.w * v.w);
  }
#pragma unroll
  for (int m2 = 32; m2; m2 >>= 1) { s += __shfl_xor(s, m2); ss += __shfl_xor(ss, m2); }
  if (lane == 0) { red[wave] = s; red[16 + wave] = ss; }
  __syncthreads();
  if (t == 0) {
    float fs = 0.f, fss = 0.f;
#pragma unroll
    for (int w = 0; w < 16; ++w) { fs += red[w]; fss += red[16 + w]; }
    float mean = fs * (1.f / 16384.f);
    float var  = fss * (1.f / 16384.f) - mean * mean;
    red[32] = mean;
    red[33] = rsqrtf(fmaxf(var, 0.f) + 1e-5f);
  }
  __syncthreads();
  const float mean = red[32], inv = red[33];
  float gm[4], bt[4];
#pragma unroll
  for (int i = 0; i < 4; ++i) {
    float ga = gamma[g * CPG + cq + i];
    gm[i] = ga * inv;
    bt[i] = beta[g * CPG + cq + i] - mean * inv * ga;
  }
  // normalize from regs; write 4 pixels x 4 channels (8B per pixel-row)
  float y0[4], y1[4], y2[4], y3[4];
#pragma unroll
  for (int i = 0; i < 4; ++i) {
    float4 v = hold[i];
    y0[i] = v.x * gm[i] + bt[i];
    y1[i] = v.y * gm[i] + bt[i];
    y2[i] = v.z * gm[i] + bt[i];
    y3[i] = v.w * gm[i] + bt[i];
  }
  u32 pk[4][2];
  pk[0][0] = (u32)f2bf(y0[0]) | ((u32)f2bf(y0[1]) << 16);
  pk[0][1] = (u32)f2bf(y0[2]) | ((u32)f2bf(y0[3]) << 16);
  pk[1][0] = (u32)f2bf(y1[0]) | ((u32)f2bf(y1[1]) << 16);
  pk[1][1] = (u32)f2bf(y1[2]) | ((u32)f2bf(y1[3]) << 16);
  pk[2][0] = (u32)f2bf(y2[0]) | ((u32)f2bf(y2[1]) << 16);
  pk[2][1] = (u32)f2bf(y2[2]) | ((u32)f2bf(y2[3]) << 16);
  pk[3][0] = (u32)f2bf(y3[0]) | ((u32)f2bf(y3[1]) << 16);
  pk[3][1] = (u32)f2bf(y3[2]) | ((u32)f2bf(y3[3]) << 16);
#pragma unroll
  for (int j = 0; j < 4; ++j) {
    u32* dst = (u32*)(xnT + (size_t)(b * NS + p4 * 4 + j) * NC + g * CPG + cq);
    dst[0] = pk[j][0];
    dst[1] = pk[j][1];
  }
}

// ---------------- K2: QKV gemm_bt (2-phase dbuf, XCD-swizzled 1D grid) -------
__global__ __launch_bounds__(256) void qkv_gemm(const u16* __restrict__ A,
                                                const u16* __restrict__ BT,
                                                const float* __restrict__ bias,
                                                u16* __restrict__ qb,
                                                u16* __restrict__ kb,
                                                u16* __restrict__ vb) {
  __shared__ char lds[32768];  // 2 x (A 8KB + B 8KB)
  const int t = threadIdx.x, wave = t >> 6, lane = t & 63;
  // XCD swizzle: 768 blocks, XCD k = lin&7 gets contiguous chunk = batch k
  int lin = blockIdx.x;
  int swz = (lin & 7) * 96 + (lin >> 3);
  const int bn = (swz & 7) * 128;
  const int bm = ((swz >> 3) % 12) * 128;
  const int bb = swz / 96;
  const u16* Bt = BT + (size_t)bb * NS * NC;
  const int wm = wave >> 1, wn = wave & 1;
  f32x4 acc[4][4];
#pragma unroll
  for (int i = 0; i < 4; ++i)
#pragma unroll
    for (int j = 0; j < 4; ++j) acc[i][j] = (f32x4){0.f, 0.f, 0.f, 0.f};

  int c0 = t, c1 = 256 + t;
  int r0 = c0 >> 2, r1 = c1 >> 2;
  int h0 = (c0 & 3) ^ ((c0 >> 3) & 3), h1 = (c1 & 3) ^ ((c1 >> 3) & 3);
  const u16* a0 = A  + (size_t)(bm + r0) * NC + h0 * 8;
  const u16* a1 = A  + (size_t)(bm + r1) * NC + h1 * 8;
  const u16* b0 = Bt + (size_t)(bn + r0) * NC + h0 * 8;
  const u16* b1 = Bt + (size_t)(bn + r1) * NC + h1 * 8;

  gll16(lds + c0 * 16, a0); gll16(lds + c1 * 16, a1);
  gll16(lds + 8192 + c0 * 16, b0); gll16(lds + 8192 + c1 * 16, b1);
  __syncthreads();

  for (int ks = 0; ks < 16; ++ks) {
    const char* cur = lds + ((ks & 1) << 14);
    if (ks < 15) {
      char* nxt = lds + (((ks + 1) & 1) << 14);
      int ko = (ks + 1) * 32;
      gll16(nxt + c0 * 16,        a0 + ko);
      gll16(nxt + c1 * 16,        a1 + ko);
      gll16(nxt + 8192 + c0 * 16, b0 + ko);
      gll16(nxt + 8192 + c1 * 16, b1 + ko);
    }
    bf16x8 af[4], bfr[4];
#pragma unroll
    for (int mf = 0; mf < 4; ++mf) {
      int row = wm * 64 + mf * 16 + (lane & 15);
      int cb = ((lane >> 4) * 16) ^ (((row >> 1) & 3) << 4);
      af[mf] = *(const bf16x8*)(cur + row * 64 + cb);
    }
#pragma unroll
    for (int nf = 0; nf < 4; ++nf) {
      int row = wn * 64 + nf * 16 + (lane & 15);
      int cb = ((lane >> 4) * 16) ^ (((row >> 1) & 3) << 4);
      bfr[nf] = *(const bf16x8*)(cur + 8192 + row * 64 + cb);
    }
#pragma unroll
    for (int mf = 0; mf < 4; ++mf)
#pragma unroll
      for (int nf = 0; nf < 4; ++nf)
        acc[mf][nf] = __builtin_amdgcn_mfma_f32_16x16x32_bf16(af[mf], bfr[nf], acc[mf][nf], 0, 0, 0);
    __syncthreads();
  }
#pragma unroll
  for (int mf = 0; mf < 4; ++mf) {
#pragma unroll
    for (int j = 0; j < 4; ++j) {
      int o = bm + wm * 64 + mf * 16 + (lane >> 4) * 4 + j;
      int n = o / 192;
      int r = o - n * 192;
      float bv = bias[o];
      size_t hb = (size_t)(bb * NH + n);
#pragma unroll
      for (int nf = 0; nf < 4; ++nf) {
        int p = bn + wn * 64 + nf * 16 + (lane & 15);
        float val = acc[mf][nf][j] + bv;
        if (r < 64)       qb[(hb * NS + p) * ND + r] = f2bf(val * SCALE_Q);
        else if (r < 128) kb[(hb * NS + p) * ND + (r - 64)] = f2bf(val);
        else              vb[(hb * ND + (r - 128)) * NS + p] = f2bf(val);
      }
    }
  }
}

// ---------------- K3: flash attention, QBLK=32/wave (XCD-swizzled 1D) --------
__global__ __launch_bounds__(256) void attn_kernel(const u16* __restrict__ qbuf,
                                                   const u16* __restrict__ kbuf,
                                                   const u16* __restrict__ vbuf,
                                                   u16* __restrict__ aoT) {
  __shared__ char lds[32768];  // 2 x (K 8KB + V 8KB)
  const int t = threadIdx.x, wave = t >> 6, lane = t & 63;
  // XCD swizzle: 512 blocks; XCD k gets bn in [8k, 8k+8) (batch k's 8 heads)
  int lin = blockIdx.x;
  int swz = (lin & 7) * 64 + (lin >> 3);
  const int qblk = swz & 7;
  const int bn = swz >> 3;
  const int b = bn >> 3, n = bn & 7;
  const u16* qp = qbuf + (size_t)bn * NS * ND;
  const char* kpb = (const char*)(kbuf + (size_t)bn * NS * ND);
  const char* vpb = (const char*)(vbuf + (size_t)bn * ND * NS);
  const int g = lane >> 4, q = lane & 15;
  const int qrowbase = qblk * 128 + wave * 32;

  bf16x8 bq[2][2];
#pragma unroll
  for (int qf = 0; qf < 2; ++qf) {
    const u16* qr = qp + (size_t)(qrowbase + qf * 16 + q) * ND + g * 8;
    bq[qf][0] = *(const bf16x8*)(qr);
    bq[qf][1] = *(const bf16x8*)(qr + 32);
  }
  int c0 = t, c1 = 256 + t;
  int lam0 = c0 >> 3, lam1 = c1 >> 3;
  int chs0 = (c0 & 7) ^ (lam0 & 7), chs1 = (c1 & 7) ^ (lam1 & 7);
  int kv0 = ((lam0 >> 5) & 1) * 32 + ((lam0 >> 4) & 1) * 4 + ((lam0 >> 2) & 3) * 8 + (lam0 & 3);
  int kv1 = ((lam1 >> 5) & 1) * 32 + ((lam1 >> 4) & 1) * 4 + ((lam1 >> 2) & 3) * 8 + (lam1 & 3);
  const char* ksrc0 = kpb + kv0 * 128 + chs0 * 16;
  const char* ksrc1 = kpb + kv1 * 128 + chs1 * 16;
  const char* vsrc0 = vpb + lam0 * 2048 + chs0 * 16;
  const char* vsrc1 = vpb + lam1 * 2048 + chs1 * 16;
  const int koffA = q * 128 + (((0 * 4 + g) ^ (q & 7)) << 4);
  const int koffB = q * 128 + (((1 * 4 + g) ^ (q & 7)) << 4);

  float m[2], l[2];
  f32x4 oacc[4][2];  // [df][qf]
#pragma unroll
  for (int qf = 0; qf < 2; ++qf) { m[qf] = -1e30f; l[qf] = 0.f; }
#pragma unroll
  for (int df = 0; df < 4; ++df)
#pragma unroll
    for (int qf = 0; qf < 2; ++qf) oacc[df][qf] = (f32x4){0.f, 0.f, 0.f, 0.f};

  gll16(lds + c0 * 16,        ksrc0);
  gll16(lds + c1 * 16,        ksrc1);
  gll16(lds + 8192 + c0 * 16, vsrc0);
  gll16(lds + 8192 + c1 * 16, vsrc1);
  drain_vm();
  __syncthreads();

  for (int kb = 0; kb < 16; ++kb) {
    const char* cur = lds + ((kb & 1) << 14);
    if (kb < 15) {
      char* nxt = lds + (((kb + 1) & 1) << 14);
      size_t ko = (size_t)(kb + 1) * 8192;
      size_t vo = (size_t)(kb + 1) * 128;
      gll16(nxt + c0 * 16,        ksrc0 + ko);
      gll16(nxt + c1 * 16,        ksrc1 + ko);
      gll16(nxt + 8192 + c0 * 16, vsrc0 + vo);
      gll16(nxt + 8192 + c1 * 16, vsrc1 + vo);
    }
    bf16x8 kf0[4], kf1[4];
#pragma unroll
    for (int cf = 0; cf < 4; ++cf) {
      kf0[cf] = *(const bf16x8*)(cur + cf * 2048 + koffA);
      kf1[cf] = *(const bf16x8*)(cur + cf * 2048 + koffB);
    }
    f32x4 s[2][4];  // [qf][cf]
#pragma unroll
    for (int qf = 0; qf < 2; ++qf)
#pragma unroll
      for (int cf = 0; cf < 4; ++cf) {
        f32x4 s0 = __builtin_amdgcn_mfma_f32_16x16x32_bf16(kf0[cf], bq[qf][0], (f32x4){0.f, 0.f, 0.f, 0.f}, 0, 0, 0);
        s[qf][cf] = __builtin_amdgcn_mfma_f32_16x16x32_bf16(kf1[cf], bq[qf][1], s0, 0, 0, 0);
      }
    const char* curv = cur + 8192;
    bf16x8 vf0[4], vf1[4];
#pragma unroll
    for (int df = 0; df < 4; ++df) {
      vf0[df] = *(const bf16x8*)(curv + df * 2048 + koffA);
      vf1[df] = *(const bf16x8*)(curv + df * 2048 + koffB);
    }
#pragma unroll
    for (int qf = 0; qf < 2; ++qf) {
      f32x4 s0 = s[qf][0], s1 = s[qf][1], s2 = s[qf][2], s3 = s[qf][3];
      float mx = fmaxf(fmaxf(fmaxf(s0[0], s0[1]), fmaxf(s0[2], s0[3])),
                       fmaxf(fmaxf(s1[0], s1[1]), fmaxf(s1[2], s1[3])));
      mx = fmaxf(mx, fmaxf(fmaxf(fmaxf(s2[0], s2[1]), fmaxf(s2[2], s2[3])),
                           fmaxf(fmaxf(s3[0], s3[1]), fmaxf(s3[2], s3[3]))));
      if (!__all(mx - m[qf] <= 8.f)) {
        float mxr = fmaxf(mx, __shfl_xor(mx, 16));
        mxr = fmaxf(mxr, __shfl_xor(mxr, 32));
        float mn = fmaxf(m[qf], mxr);
        float sc = exp2_fast(m[qf] - mn);
        m[qf] = mn;
        l[qf] *= sc;
#pragma unroll
        for (int df = 0; df < 4; ++df) {
          f32x4 o2 = oacc[df][qf];
          o2[0] *= sc; o2[1] *= sc; o2[2] *= sc; o2[3] *= sc;
          oacc[df][qf] = o2;
        }
      }
      float mm = m[qf], ll = l[qf];
      float p00 = exp2_fast(s0[0] - mm), p01 = exp2_fast(s0[1] - mm);
      float p02 = exp2_fast(s0[2] - mm), p03 = exp2_fast(s0[3] - mm);
      float p10 = exp2_fast(s1[0] - mm), p11 = exp2_fast(s1[1] - mm);
      float p12 = exp2_fast(s1[2] - mm), p13 = exp2_fast(s1[3] - mm);
      float p20 = exp2_fast(s2[0] - mm), p21 = exp2_fast(s2[1] - mm);
      float p22 = exp2_fast(s2[2] - mm), p23 = exp2_fast(s2[3] - mm);
      float p30 = exp2_fast(s3[0] - mm), p31 = exp2_fast(s3[1] - mm);
      float p32 = exp2_fast(s3[2] - mm), p33 = exp2_fast(s3[3] - mm);
      ll += ((p00 + p01) + (p02 + p03)) + ((p10 + p11) + (p12 + p13)) +
            ((p20 + p21) + (p22 + p23)) + ((p30 + p31) + (p32 + p33));
      l[qf] = ll;
      u32x4 w0, w1;
      w0[0] = cvtpk_bf16(p00, p01); w0[1] = cvtpk_bf16(p02, p03);
      w0[2] = cvtpk_bf16(p10, p11); w0[3] = cvtpk_bf16(p12, p13);
      w1[0] = cvtpk_bf16(p20, p21); w1[1] = cvtpk_bf16(p22, p23);
      w1[2] = cvtpk_bf16(p30, p31); w1[3] = cvtpk_bf16(p32, p33);
      bf16x8 pb0 = __builtin_bit_cast(bf16x8, w0);
      bf16x8 pb1 = __builtin_bit_cast(bf16x8, w1);
#pragma unroll
      for (int df = 0; df < 4; ++df) {
        oacc[df][qf] = __builtin_amdgcn_mfma_f32_16x16x32_bf16(vf0[df], pb0, oacc[df][qf], 0, 0, 0);
        oacc[df][qf] = __builtin_amdgcn_mfma_f32_16x16x32_bf16(vf1[df], pb1, oacc[df][qf], 0, 0, 0);
      }
    }
    drain_vm();
    __syncthreads();
  }
  char* myT = lds + wave * 2048;
#pragma unroll
  for (int qf = 0; qf < 2; ++qf) {
    float ll = l[qf];
    ll += __shfl_xor(ll, 16);
    ll += __shfl_xor(ll, 32);
    const float inv = 1.f / ll;
#pragma unroll
    for (int df = 0; df < 4; ++df)
#pragma unroll
      for (int h = 0; h < 2; ++h) {
        u32 w = cvtpk_bf16(oacc[df][qf][2 * h] * inv, oacc[df][qf][2 * h + 1] * inv);
        int X = (df * 16 + 4 * g + 2 * h) * 2;
        *(u32*)(myT + q * 128 + (X ^ ((q & 7) << 4))) = w;
      }
#pragma unroll
    for (int h = 0; h < 2; ++h) {
      int q2 = h * 8 + (lane >> 3);
      int c = lane & 7;
      bf16x8 vrow = *(const bf16x8*)(myT + q2 * 128 + ((c * 16) ^ ((q2 & 7) << 4)));
      int prow = qrowbase + qf * 16 + q2;
      *(bf16x8*)(aoT + (size_t)(b * NS + prow) * NC + n * 64 + c * 8) = vrow;
    }
  }
}

// ---------------- K4: out gemm_bt + bias + residual (XCD-swizzled 1D) --------
__global__ __launch_bounds__(256) void out_gemm(const u16* __restrict__ A,
                                                const u16* __restrict__ BT,
                                                const float* __restrict__ bias,
                                                const float* __restrict__ xres,
                                                float* __restrict__ out) {
  __shared__ char lds[32768];
  const int t = threadIdx.x, wave = t >> 6, lane = t & 63;
  // XCD swizzle: 256 blocks; XCD k gets batch k
  int lin = blockIdx.x;
  int swz = (lin & 7) * 32 + (lin >> 3);
  const int bn = (swz & 7) * 128;
  const int bm = ((swz >> 3) & 3) * 128;
  const int bb = swz >> 5;
  const u16* Bt = BT + (size_t)bb * NS * NC;
  const int wm = wave >> 1, wn = wave & 1;
  f32x4 acc[4][4];
#pragma unroll
  for (int i = 0; i < 4; ++i)
#pragma unroll
    for (int j = 0; j < 4; ++j) acc[i][j] = (f32x4){0.f, 0.f, 0.f, 0.f};

  int c0 = t, c1 = 256 + t;
  int r0 = c0 >> 2, r1 = c1 >> 2;
  int h0 = (c0 & 3) ^ ((c0 >> 3) & 3), h1 = (c1 & 3) ^ ((c1 >> 3) & 3);
  const u16* a0 = A  + (size_t)(bm + r0) * NC + h0 * 8;
  const u16* a1 = A  + (size_t)(bm + r1) * NC + h1 * 8;
  const u16* b0 = Bt + (size_t)(bn + r0) * NC + h0 * 8;
  const u16* b1 = Bt + (size_t)(bn + r1) * NC + h1 * 8;

  gll16(lds + c0 * 16, a0); gll16(lds + c1 * 16, a1);
  gll16(lds + 8192 + c0 * 16, b0); gll16(lds + 8192 + c1 * 16, b1);
  __syncthreads();

  for (int ks = 0; ks < 16; ++ks) {
    const char* cur = lds + ((ks & 1) << 14);
    if (ks < 15) {
      char* nxt = lds + (((ks + 1) & 1) << 14);
      int ko = (ks + 1) * 32;
      gll16(nxt + c0 * 16,        a0 + ko);
      gll16(nxt + c1 * 16,        a1 + ko);
      gll16(nxt + 8192 + c0 * 16, b0 + ko);
      gll16(nxt + 8192 + c1 * 16, b1 + ko);
    }
    bf16x8 af[4], bfr[4];
#pragma unroll
    for (int mf = 0; mf < 4; ++mf) {
      int row = wm * 64 + mf * 16 + (lane & 15);
      int cb = ((lane >> 4) * 16) ^ (((row >> 1) & 3) << 4);
      af[mf] = *(const bf16x8*)(cur + row * 64 + cb);
    }
#pragma unroll
    for (int nf = 0; nf < 4; ++nf) {
      int row = wn * 64 + nf * 16 + (lane & 15);
      int cb = ((lane >> 4) * 16) ^ (((row >> 1) & 3) << 4);
      bfr[nf] = *(const bf16x8*)(cur + 8192 + row * 64 + cb);
    }
#pragma unroll
    for (int mf = 0; mf < 4; ++mf)
#pragma unroll
      for (int nf = 0; nf < 4; ++nf)
        acc[mf][nf] = __builtin_amdgcn_mfma_f32_16x16x32_bf16(af[mf], bfr[nf], acc[mf][nf], 0, 0, 0);
    __syncthreads();
  }
#pragma unroll
  for (int mf = 0; mf < 4; ++mf) {
#pragma unroll
    for (int j = 0; j < 4; ++j) {
      int o = bm + wm * 64 + mf * 16 + (lane >> 4) * 4 + j;
      float bv = bias[o];
#pragma unroll
      for (int nf = 0; nf < 4; ++nf) {
        int p = bn + wn * 64 + nf * 16 + (lane & 15);
        size_t idx = (size_t)(bb * NC + o) * NS + p;
        out[idx] = acc[mf][nf][j] + bv + xres[idx];
      }
    }
  }
}

extern "C" void kernel_launch(void* const* d_in, const int* in_sizes, int n_in,
                              void* d_out, int out_size, void* d_ws, size_t ws_size,
                              hipStream_t stream) {
  const float* x     = (const float*)d_in[0];
  const float* gn_w  = (const float*)d_in[1];
  const float* gn_b  = (const float*)d_in[2];
  const float* qkv_w = (const float*)d_in[3];
  const float* qkv_b = (const float*)d_in[4];
  const float* out_w = (const float*)d_in[5];
  const float* out_b = (const float*)d_in[6];
  float* out = (float*)d_out;
  char* ws = (char*)d_ws;

  u16* wq  = (u16*)(ws);
  u16* wo  = (u16*)(ws + 1572864);
  u16* xnT = (u16*)(ws + 2097152);
  u16* kb  = (u16*)(ws + 10485760);
  u16* vb  = (u16*)(ws + 18874368);
  u16* aoT = (u16*)(ws + 2097152);   // overlaps xnT (sequentially dead)
  u16* qb  = (u16*)d_out;            // scratch use of d_out; overwritten by out_gemm

  wconv_kernel<<<dim3(1024), dim3(256), 0, stream>>>(qkv_w, out_w, wq, wo);
  gn_kernel<<<dim3(NB * NG), dim3(1024), 0, stream>>>(x, gn_w, gn_b, xnT);
  qkv_gemm<<<dim3(768), dim3(256), 0, stream>>>(wq, xnT, qkv_b, qb, kb, vb);
  attn_kernel<<<dim3(512), dim3(256), 0, stream>>>(qb, kb, vb, aoT);
  out_gemm<<<dim3(256), dim3(256), 0, stream>>>(wo, aoT, out_b, x, out);
}

// Round 11
// 95.343 us; speedup vs baseline: 1.3743x; 1.0190x over previous
//
#include <hip/hip_runtime.h>
#include <math.h>

typedef unsigned short u16;
typedef unsigned int   u32;
typedef __attribute__((ext_vector_type(8))) short bf16x8;
typedef __attribute__((ext_vector_type(4))) float f32x4;
typedef __attribute__((ext_vector_type(4))) u32   u32x4;

#define NB 8
#define NC 512
#define NS 1024
#define NH 8
#define ND 64
#define NG 32
#define CPG 16
#define SCALE_Q 0.18033688f  /* 0.125 * log2(e): softmax runs in exp2 domain */

__device__ __forceinline__ u16 f2bf(float x) {
  u32 u = __builtin_bit_cast(u32, x);
  u = u + 0x7fffu + ((u >> 16) & 1u);
  return (u16)(u >> 16);
}

__device__ __forceinline__ float exp2_fast(float x) {
  float r;
  asm("v_exp_f32 %0, %1" : "=v"(r) : "v"(x));
  return r;
}

__device__ __forceinline__ u32 cvtpk_bf16(float lo, float hi) {
  u32 r;
  asm("v_cvt_pk_bf16_f32 %0, %1, %2" : "=v"(r) : "v"(lo), "v"(hi));
  return r;
}

__device__ __forceinline__ void gll16(void* l, const void* g) {
  __builtin_amdgcn_global_load_lds((const __attribute__((address_space(1))) void*)g,
                                   (__attribute__((address_space(3))) void*)l, 16, 0, 0);
}

__device__ __forceinline__ void drain_vm() {
  asm volatile("s_waitcnt vmcnt(0)" ::: "memory");
}

// ---------------- K0: weight fp32 -> bf16 ----------------
__global__ __launch_bounds__(256) void wconv_kernel(const float* __restrict__ qkvw,
                                                    const float* __restrict__ outw,
                                                    u16* __restrict__ wq,
                                                    u16* __restrict__ wo) {
  int i = (blockIdx.x * 256 + threadIdx.x) * 4;
  const int NQ = 3 * NC * NC;
  const float* src;
  u16* dst;
  int off;
  if (i < NQ) { src = qkvw; dst = wq; off = i; }
  else        { src = outw; dst = wo; off = i - NQ; }
  float4 v = *(const float4*)(src + off);
  u32 lo = (u32)f2bf(v.x) | ((u32)f2bf(v.y) << 16);
  u32 hi = (u32)f2bf(v.z) | ((u32)f2bf(v.w) << 16);
  u32* p = (u32*)(dst + off);
  p[0] = lo; p[1] = hi;
}

// ---------------- K1: GroupNorm -> xnT[b][p][c] bf16 (single-pass, 1024 thr) --
__global__ __launch_bounds__(1024) void gn_kernel(const float* __restrict__ x,
                                                  const float* __restrict__ gamma,
                                                  const float* __restrict__ beta,
                                                  u16* __restrict__ xnT) {
  __shared__ float red[34];
  const int t = threadIdx.x;
  const int wave = t >> 6, lane = t & 63;
  const int b = blockIdx.x >> 5, g = blockIdx.x & 31;
  const float* xb = x + (size_t)(b * NC + g * CPG) * NS;
  const int p4 = t >> 2;
  const int cq = (t & 3) * 4;

  float4 hold[4];
  float s = 0.f, ss = 0.f;
#pragma unroll
  for (int i = 0; i < 4; ++i) {
    float4 v = ((const float4*)xb)[(cq + i) * 256 + p4];
    hold[i] = v;
    s  += (v.x + v.y) + (v.z + v.w);
    ss += (v.x * v.x + v.y * v.y) + (v.z * v.z + v.w * v.w);
  }
#pragma unroll
  for (int m2 = 32; m2; m2 >>= 1) { s += __shfl_xor(s, m2); ss += __shfl_xor(ss, m2); }
  if (lane == 0) { red[wave] = s; red[16 + wave] = ss; }
  __syncthreads();
  if (t == 0) {
    float fs = 0.f, fss = 0.f;
#pragma unroll
    for (int w = 0; w < 16; ++w) { fs += red[w]; fss += red[16 + w]; }
    float mean = fs * (1.f / 16384.f);
    float var  = fss * (1.f / 16384.f) - mean * mean;
    red[32] = mean;
    red[33] = rsqrtf(fmaxf(var, 0.f) + 1e-5f);
  }
  __syncthreads();
  const float mean = red[32], inv = red[33];
  float gm[4], bt[4];
#pragma unroll
  for (int i = 0; i < 4; ++i) {
    float ga = gamma[g * CPG + cq + i];
    gm[i] = ga * inv;
    bt[i] = beta[g * CPG + cq + i] - mean * inv * ga;
  }
  float y0[4], y1[4], y2[4], y3[4];
#pragma unroll
  for (int i = 0; i < 4; ++i) {
    float4 v = hold[i];
    y0[i] = v.x * gm[i] + bt[i];
    y1[i] = v.y * gm[i] + bt[i];
    y2[i] = v.z * gm[i] + bt[i];
    y3[i] = v.w * gm[i] + bt[i];
  }
  u32 pk[4][2];
  pk[0][0] = (u32)f2bf(y0[0]) | ((u32)f2bf(y0[1]) << 16);
  pk[0][1] = (u32)f2bf(y0[2]) | ((u32)f2bf(y0[3]) << 16);
  pk[1][0] = (u32)f2bf(y1[0]) | ((u32)f2bf(y1[1]) << 16);
  pk[1][1] = (u32)f2bf(y1[2]) | ((u32)f2bf(y1[3]) << 16);
  pk[2][0] = (u32)f2bf(y2[0]) | ((u32)f2bf(y2[1]) << 16);
  pk[2][1] = (u32)f2bf(y2[2]) | ((u32)f2bf(y2[3]) << 16);
  pk[3][0] = (u32)f2bf(y3[0]) | ((u32)f2bf(y3[1]) << 16);
  pk[3][1] = (u32)f2bf(y3[2]) | ((u32)f2bf(y3[3]) << 16);
#pragma unroll
  for (int j = 0; j < 4; ++j) {
    u32* dst = (u32*)(xnT + (size_t)(b * NS + p4 * 4 + j) * NC + g * CPG + cq);
    dst[0] = pk[j][0];
    dst[1] = pk[j][1];
  }
}

// ---------------- K2: QKV gemm_bt (2-phase dbuf, XCD-swizzled 1D grid) -------
__global__ __launch_bounds__(256) void qkv_gemm(const u16* __restrict__ A,
                                                const u16* __restrict__ BT,
                                                const float* __restrict__ bias,
                                                u16* __restrict__ qb,
                                                u16* __restrict__ kb,
                                                u16* __restrict__ vb) {
  __shared__ char lds[32768];  // 2 x (A 8KB + B 8KB)
  const int t = threadIdx.x, wave = t >> 6, lane = t & 63;
  int lin = blockIdx.x;
  int swz = (lin & 7) * 96 + (lin >> 3);
  const int bn = (swz & 7) * 128;
  const int bm = ((swz >> 3) % 12) * 128;
  const int bb = swz / 96;
  const u16* Bt = BT + (size_t)bb * NS * NC;
  const int wm = wave >> 1, wn = wave & 1;
  f32x4 acc[4][4];
#pragma unroll
  for (int i = 0; i < 4; ++i)
#pragma unroll
    for (int j = 0; j < 4; ++j) acc[i][j] = (f32x4){0.f, 0.f, 0.f, 0.f};

  int c0 = t, c1 = 256 + t;
  int r0 = c0 >> 2, r1 = c1 >> 2;
  int h0 = (c0 & 3) ^ ((c0 >> 3) & 3), h1 = (c1 & 3) ^ ((c1 >> 3) & 3);
  const u16* a0 = A  + (size_t)(bm + r0) * NC + h0 * 8;
  const u16* a1 = A  + (size_t)(bm + r1) * NC + h1 * 8;
  const u16* b0 = Bt + (size_t)(bn + r0) * NC + h0 * 8;
  const u16* b1 = Bt + (size_t)(bn + r1) * NC + h1 * 8;

  gll16(lds + c0 * 16, a0); gll16(lds + c1 * 16, a1);
  gll16(lds + 8192 + c0 * 16, b0); gll16(lds + 8192 + c1 * 16, b1);
  __syncthreads();

  for (int ks = 0; ks < 16; ++ks) {
    const char* cur = lds + ((ks & 1) << 14);
    if (ks < 15) {
      char* nxt = lds + (((ks + 1) & 1) << 14);
      int ko = (ks + 1) * 32;
      gll16(nxt + c0 * 16,        a0 + ko);
      gll16(nxt + c1 * 16,        a1 + ko);
      gll16(nxt + 8192 + c0 * 16, b0 + ko);
      gll16(nxt + 8192 + c1 * 16, b1 + ko);
    }
    bf16x8 af[4], bfr[4];
#pragma unroll
    for (int mf = 0; mf < 4; ++mf) {
      int row = wm * 64 + mf * 16 + (lane & 15);
      int cb = ((lane >> 4) * 16) ^ (((row >> 1) & 3) << 4);
      af[mf] = *(const bf16x8*)(cur + row * 64 + cb);
    }
#pragma unroll
    for (int nf = 0; nf < 4; ++nf) {
      int row = wn * 64 + nf * 16 + (lane & 15);
      int cb = ((lane >> 4) * 16) ^ (((row >> 1) & 3) << 4);
      bfr[nf] = *(const bf16x8*)(cur + 8192 + row * 64 + cb);
    }
#pragma unroll
    for (int mf = 0; mf < 4; ++mf)
#pragma unroll
      for (int nf = 0; nf < 4; ++nf)
        acc[mf][nf] = __builtin_amdgcn_mfma_f32_16x16x32_bf16(af[mf], bfr[nf], acc[mf][nf], 0, 0, 0);
    __syncthreads();
  }
#pragma unroll
  for (int mf = 0; mf < 4; ++mf) {
#pragma unroll
    for (int j = 0; j < 4; ++j) {
      int o = bm + wm * 64 + mf * 16 + (lane >> 4) * 4 + j;
      int n = o / 192;
      int r = o - n * 192;
      float bv = bias[o];
      size_t hb = (size_t)(bb * NH + n);
#pragma unroll
      for (int nf = 0; nf < 4; ++nf) {
        int p = bn + wn * 64 + nf * 16 + (lane & 15);
        float val = acc[mf][nf][j] + bv;
        if (r < 64)       qb[(hb * NS + p) * ND + r] = f2bf(val * SCALE_Q);
        else if (r < 128) kb[(hb * NS + p) * ND + (r - 64)] = f2bf(val);
        else              vb[(hb * ND + (r - 128)) * NS + p] = f2bf(val);
      }
    }
  }
}

// ---------------- K3: flash attention, fixed-max softmax, KVBLK=128 ----------
// Softmax is shift-invariant: P=exp2(S-8) with CONSTANT 8 (|S|<~9 by bound
// analysis; overflow needs 94 sigma) -> no max tree, no cross-lane reduce, no
// rescale, no m-state. 2 sub-tiles per barrier (8 barriers, was 16).
__global__ __launch_bounds__(256) void attn_kernel(const u16* __restrict__ qbuf,
                                                   const u16* __restrict__ kbuf,
                                                   const u16* __restrict__ vbuf,
                                                   u16* __restrict__ aoT) {
  __shared__ char lds[65536];  // 2 x (K0 8K | V0 8K | K1 8K | V1 8K)
  const int t = threadIdx.x, wave = t >> 6, lane = t & 63;
  int lin = blockIdx.x;
  int swz = (lin & 7) * 64 + (lin >> 3);
  const int qblk = swz & 7;
  const int bn = swz >> 3;
  const int b = bn >> 3, n = bn & 7;
  const u16* qp = qbuf + (size_t)bn * NS * ND;
  const char* kpb = (const char*)(kbuf + (size_t)bn * NS * ND);
  const char* vpb = (const char*)(vbuf + (size_t)bn * ND * NS);
  const int g = lane >> 4, q = lane & 15;
  const int qrowbase = qblk * 128 + wave * 32;

  bf16x8 bq[2][2];
#pragma unroll
  for (int qf = 0; qf < 2; ++qf) {
    const u16* qr = qp + (size_t)(qrowbase + qf * 16 + q) * ND + g * 8;
    bq[qf][0] = *(const bf16x8*)(qr);
    bq[qf][1] = *(const bf16x8*)(qr + 32);
  }
  int c0 = t, c1 = 256 + t;
  int lam0 = c0 >> 3, lam1 = c1 >> 3;
  int chs0 = (c0 & 7) ^ (lam0 & 7), chs1 = (c1 & 7) ^ (lam1 & 7);
  int kv0 = ((lam0 >> 5) & 1) * 32 + ((lam0 >> 4) & 1) * 4 + ((lam0 >> 2) & 3) * 8 + (lam0 & 3);
  int kv1 = ((lam1 >> 5) & 1) * 32 + ((lam1 >> 4) & 1) * 4 + ((lam1 >> 2) & 3) * 8 + (lam1 & 3);
  const char* ksrc0 = kpb + kv0 * 128 + chs0 * 16;
  const char* ksrc1 = kpb + kv1 * 128 + chs1 * 16;
  const char* vsrc0 = vpb + lam0 * 2048 + chs0 * 16;
  const char* vsrc1 = vpb + lam1 * 2048 + chs1 * 16;
  const int koffA = q * 128 + (((0 * 4 + g) ^ (q & 7)) << 4);
  const int koffB = q * 128 + (((1 * 4 + g) ^ (q & 7)) << 4);

  float l[2];
  f32x4 oacc[4][2];  // [df][qf]
  l[0] = 0.f; l[1] = 0.f;
#pragma unroll
  for (int df = 0; df < 4; ++df)
#pragma unroll
    for (int qf = 0; qf < 2; ++qf) oacc[df][qf] = (f32x4){0.f, 0.f, 0.f, 0.f};

  // prologue: stage tile pair {0,1} into buffer 0
#pragma unroll
  for (int sst = 0; sst < 2; ++sst) {
    char* dst = lds + sst * 16384;
    gll16(dst + c0 * 16,        ksrc0 + (size_t)sst * 8192);
    gll16(dst + c1 * 16,        ksrc1 + (size_t)sst * 8192);
    gll16(dst + 8192 + c0 * 16, vsrc0 + (size_t)sst * 128);
    gll16(dst + 8192 + c1 * 16, vsrc1 + (size_t)sst * 128);
  }
  drain_vm();
  __syncthreads();

  for (int j = 0; j < 8; ++j) {
    const char* cur = lds + (j & 1) * 32768;
    if (j < 7) {
      char* nxt = lds + ((j + 1) & 1) * 32768;
#pragma unroll
      for (int sst = 0; sst < 2; ++sst) {
        int kb = 2 * (j + 1) + sst;
        char* dst = nxt + sst * 16384;
        gll16(dst + c0 * 16,        ksrc0 + (size_t)kb * 8192);
        gll16(dst + c1 * 16,        ksrc1 + (size_t)kb * 8192);
        gll16(dst + 8192 + c0 * 16, vsrc0 + (size_t)kb * 128);
        gll16(dst + 8192 + c1 * 16, vsrc1 + (size_t)kb * 128);
      }
    }
#pragma unroll
    for (int sst = 0; sst < 2; ++sst) {
      const char* curs = cur + sst * 16384;
      bf16x8 kf0[4], kf1[4];
#pragma unroll
      for (int cf = 0; cf < 4; ++cf) {
        kf0[cf] = *(const bf16x8*)(curs + cf * 2048 + koffA);
        kf1[cf] = *(const bf16x8*)(curs + cf * 2048 + koffB);
      }
      f32x4 s[2][4];  // [qf][cf]
#pragma unroll
      for (int qf = 0; qf < 2; ++qf)
#pragma unroll
        for (int cf = 0; cf < 4; ++cf) {
          f32x4 s0 = __builtin_amdgcn_mfma_f32_16x16x32_bf16(kf0[cf], bq[qf][0], (f32x4){0.f, 0.f, 0.f, 0.f}, 0, 0, 0);
          s[qf][cf] = __builtin_amdgcn_mfma_f32_16x16x32_bf16(kf1[cf], bq[qf][1], s0, 0, 0, 0);
        }
      const char* curv = curs + 8192;
      bf16x8 vf0[4], vf1[4];
#pragma unroll
      for (int df = 0; df < 4; ++df) {
        vf0[df] = *(const bf16x8*)(curv + df * 2048 + koffA);
        vf1[df] = *(const bf16x8*)(curv + df * 2048 + koffB);
      }
#pragma unroll
      for (int qf = 0; qf < 2; ++qf) {
        f32x4 s0 = s[qf][0], s1 = s[qf][1], s2 = s[qf][2], s3 = s[qf][3];
        // fixed-max softmax: P = exp2(S - 8); exactly cancels in O/l
        float p00 = exp2_fast(s0[0] - 8.f), p01 = exp2_fast(s0[1] - 8.f);
        float p02 = exp2_fast(s0[2] - 8.f), p03 = exp2_fast(s0[3] - 8.f);
        float p10 = exp2_fast(s1[0] - 8.f), p11 = exp2_fast(s1[1] - 8.f);
        float p12 = exp2_fast(s1[2] - 8.f), p13 = exp2_fast(s1[3] - 8.f);
        float p20 = exp2_fast(s2[0] - 8.f), p21 = exp2_fast(s2[1] - 8.f);
        float p22 = exp2_fast(s2[2] - 8.f), p23 = exp2_fast(s2[3] - 8.f);
        float p30 = exp2_fast(s3[0] - 8.f), p31 = exp2_fast(s3[1] - 8.f);
        float p32 = exp2_fast(s3[2] - 8.f), p33 = exp2_fast(s3[3] - 8.f);
        l[qf] += ((p00 + p01) + (p02 + p03)) + ((p10 + p11) + (p12 + p13)) +
                 ((p20 + p21) + (p22 + p23)) + ((p30 + p31) + (p32 + p33));
        u32x4 w0, w1;
        w0[0] = cvtpk_bf16(p00, p01); w0[1] = cvtpk_bf16(p02, p03);
        w0[2] = cvtpk_bf16(p10, p11); w0[3] = cvtpk_bf16(p12, p13);
        w1[0] = cvtpk_bf16(p20, p21); w1[1] = cvtpk_bf16(p22, p23);
        w1[2] = cvtpk_bf16(p30, p31); w1[3] = cvtpk_bf16(p32, p33);
        bf16x8 pb0 = __builtin_bit_cast(bf16x8, w0);
        bf16x8 pb1 = __builtin_bit_cast(bf16x8, w1);
#pragma unroll
        for (int df = 0; df < 4; ++df) {
          oacc[df][qf] = __builtin_amdgcn_mfma_f32_16x16x32_bf16(vf0[df], pb0, oacc[df][qf], 0, 0, 0);
          oacc[df][qf] = __builtin_amdgcn_mfma_f32_16x16x32_bf16(vf1[df], pb1, oacc[df][qf], 0, 0, 0);
        }
      }
    }
    drain_vm();
    __syncthreads();
  }
  // epilogue: transpose via wave-private swizzled patch in buffer-0 K0 region
  char* myT = lds + wave * 2048;
#pragma unroll
  for (int qf = 0; qf < 2; ++qf) {
    float ll = l[qf];
    ll += __shfl_xor(ll, 16);
    ll += __shfl_xor(ll, 32);
    const float inv = 1.f / ll;
#pragma unroll
    for (int df = 0; df < 4; ++df)
#pragma unroll
      for (int h = 0; h < 2; ++h) {
        u32 w = cvtpk_bf16(oacc[df][qf][2 * h] * inv, oacc[df][qf][2 * h + 1] * inv);
        int X = (df * 16 + 4 * g + 2 * h) * 2;
        *(u32*)(myT + q * 128 + (X ^ ((q & 7) << 4))) = w;
      }
#pragma unroll
    for (int h = 0; h < 2; ++h) {
      int q2 = h * 8 + (lane >> 3);
      int c = lane & 7;
      bf16x8 vrow = *(const bf16x8*)(myT + q2 * 128 + ((c * 16) ^ ((q2 & 7) << 4)));
      int prow = qrowbase + qf * 16 + q2;
      *(bf16x8*)(aoT + (size_t)(b * NS + prow) * NC + n * 64 + c * 8) = vrow;
    }
  }
}

// ---------------- K4: out gemm_bt + bias + residual (XCD-swizzled 1D) --------
__global__ __launch_bounds__(256) void out_gemm(const u16* __restrict__ A,
                                                const u16* __restrict__ BT,
                                                const float* __restrict__ bias,
                                                const float* __restrict__ xres,
                                                float* __restrict__ out) {
  __shared__ char lds[32768];
  const int t = threadIdx.x, wave = t >> 6, lane = t & 63;
  int lin = blockIdx.x;
  int swz = (lin & 7) * 32 + (lin >> 3);
  const int bn = (swz & 7) * 128;
  const int bm = ((swz >> 3) & 3) * 128;
  const int bb = swz >> 5;
  const u16* Bt = BT + (size_t)bb * NS * NC;
  const int wm = wave >> 1, wn = wave & 1;
  f32x4 acc[4][4];
#pragma unroll
  for (int i = 0; i < 4; ++i)
#pragma unroll
    for (int j = 0; j < 4; ++j) acc[i][j] = (f32x4){0.f, 0.f, 0.f, 0.f};

  int c0 = t, c1 = 256 + t;
  int r0 = c0 >> 2, r1 = c1 >> 2;
  int h0 = (c0 & 3) ^ ((c0 >> 3) & 3), h1 = (c1 & 3) ^ ((c1 >> 3) & 3);
  const u16* a0 = A  + (size_t)(bm + r0) * NC + h0 * 8;
  const u16* a1 = A  + (size_t)(bm + r1) * NC + h1 * 8;
  const u16* b0 = Bt + (size_t)(bn + r0) * NC + h0 * 8;
  const u16* b1 = Bt + (size_t)(bn + r1) * NC + h1 * 8;

  gll16(lds + c0 * 16, a0); gll16(lds + c1 * 16, a1);
  gll16(lds + 8192 + c0 * 16, b0); gll16(lds + 8192 + c1 * 16, b1);
  __syncthreads();

  for (int ks = 0; ks < 16; ++ks) {
    const char* cur = lds + ((ks & 1) << 14);
    if (ks < 15) {
      char* nxt = lds + (((ks + 1) & 1) << 14);
      int ko = (ks + 1) * 32;
      gll16(nxt + c0 * 16,        a0 + ko);
      gll16(nxt + c1 * 16,        a1 + ko);
      gll16(nxt + 8192 + c0 * 16, b0 + ko);
      gll16(nxt + 8192 + c1 * 16, b1 + ko);
    }
    bf16x8 af[4], bfr[4];
#pragma unroll
    for (int mf = 0; mf < 4; ++mf) {
      int row = wm * 64 + mf * 16 + (lane & 15);
      int cb = ((lane >> 4) * 16) ^ (((row >> 1) & 3) << 4);
      af[mf] = *(const bf16x8*)(cur + row * 64 + cb);
    }
#pragma unroll
    for (int nf = 0; nf < 4; ++nf) {
      int row = wn * 64 + nf * 16 + (lane & 15);
      int cb = ((lane >> 4) * 16) ^ (((row >> 1) & 3) << 4);
      bfr[nf] = *(const bf16x8*)(cur + 8192 + row * 64 + cb);
    }
#pragma unroll
    for (int mf = 0; mf < 4; ++mf)
#pragma unroll
      for (int nf = 0; nf < 4; ++nf)
        acc[mf][nf] = __builtin_amdgcn_mfma_f32_16x16x32_bf16(af[mf], bfr[nf], acc[mf][nf], 0, 0, 0);
    __syncthreads();
  }
#pragma unroll
  for (int mf = 0; mf < 4; ++mf) {
#pragma unroll
    for (int j = 0; j < 4; ++j) {
      int o = bm + wm * 64 + mf * 16 + (lane >> 4) * 4 + j;
      float bv = bias[o];
#pragma unroll
      for (int nf = 0; nf < 4; ++nf) {
        int p = bn + wn * 64 + nf * 16 + (lane & 15);
        size_t idx = (size_t)(bb * NC + o) * NS + p;
        out[idx] = acc[mf][nf][j] + bv + xres[idx];
      }
    }
  }
}

extern "C" void kernel_launch(void* const* d_in, const int* in_sizes, int n_in,
                              void* d_out, int out_size, void* d_ws, size_t ws_size,
                              hipStream_t stream) {
  const float* x     = (const float*)d_in[0];
  const float* gn_w  = (const float*)d_in[1];
  const float* gn_b  = (const float*)d_in[2];
  const float* qkv_w = (const float*)d_in[3];
  const float* qkv_b = (const float*)d_in[4];
  const float* out_w = (const float*)d_in[5];
  const float* out_b = (const float*)d_in[6];
  float* out = (float*)d_out;
  char* ws = (char*)d_ws;

  u16* wq  = (u16*)(ws);
  u16* wo  = (u16*)(ws + 1572864);
  u16* xnT = (u16*)(ws + 2097152);
  u16* kb  = (u16*)(ws + 10485760);
  u16* vb  = (u16*)(ws + 18874368);
  u16* aoT = (u16*)(ws + 2097152);   // overlaps xnT (sequentially dead)
  u16* qb  = (u16*)d_out;            // scratch use of d_out; overwritten by out_gemm

  wconv_kernel<<<dim3(1024), dim3(256), 0, stream>>>(qkv_w, out_w, wq, wo);
  gn_kernel<<<dim3(NB * NG), dim3(1024), 0, stream>>>(x, gn_w, gn_b, xnT);
  qkv_gemm<<<dim3(768), dim3(256), 0, stream>>>(wq, xnT, qkv_b, qb, kb, vb);
  attn_kernel<<<dim3(512), dim3(256), 0, stream>>>(qb, kb, vb, aoT);
  out_gemm<<<dim3(256), dim3(256), 0, stream>>>(wo, aoT, out_b, x, out);
}